// Round 7
// baseline (627.331 us; speedup 1.0000x reference)
//
#include <hip/hip_runtime.h>
#include <hip/hip_bf16.h>
#include <stdint.h>
#include <stddef.h>

#define B_ 4
#define S_ 2048
#define D_ 1024
#define H_ 16
#define HD_ 64
#define NTOK (B_*S_)      // 8192
#define HDIM (H_*HD_)     // 1024
#define LOG2E 1.44269504088896f

typedef __bf16 bf16_t;
typedef __bf16 bf16x4 __attribute__((ext_vector_type(4)));
typedef __bf16 bf16x8 __attribute__((ext_vector_type(8)));
typedef short shortx4 __attribute__((ext_vector_type(4)));
typedef float floatx4 __attribute__((ext_vector_type(4)));

#define MFMA16(a,b,c)  __builtin_amdgcn_mfma_f32_16x16x32_bf16((a),(b),(c),0,0,0)
#define MFMA1K(a,b,c)  __builtin_amdgcn_mfma_f32_16x16x16bf16_1k((a),(b),(c),0,0,0)

// async global->LDS, 16 B per lane; LDS dst must be wave-uniform-base + lane*16
__device__ __forceinline__ void async_cp16(const bf16_t* g, bf16_t* l) {
    typedef __attribute__((address_space(1))) const unsigned int gu32;
    typedef __attribute__((address_space(3))) unsigned int lu32;
    __builtin_amdgcn_global_load_lds((gu32*)g, (lu32*)l, 16, 0, 0);
}

// ---------------- fp32 -> bf16 bulk convert (5 segments) ----------------
struct Cvt5 { const float* s[5]; bf16_t* d[5]; int n4[5]; };

__global__ __launch_bounds__(256) void cvt5(Cvt5 p) {
    const int z = blockIdx.y;
    const float4* __restrict__ src = (const float4*)p.s[z];
    bf16x4* __restrict__ dst = (bf16x4*)p.d[z];
    const int n4 = p.n4[z];
    for (int i = blockIdx.x * 256 + threadIdx.x; i < n4; i += gridDim.x * 256) {
        const float4 v = src[i];
        dst[i] = (bf16x4){(bf16_t)v.x, (bf16_t)v.y, (bf16_t)v.z, (bf16_t)v.w};
    }
}

// ---------------- NT GEMM, BK=64 (dual stride-32 buffers) -----------------
struct GemmPtrs { const bf16_t* A[3]; const bf16_t* W[3]; void* C[3]; };

template<int MODE>
__global__ __launch_bounds__(256, 3) void gemm_nt(GemmPtrs p, int K) {
    __shared__ bf16_t lA0[128*32], lA1[128*32];
    __shared__ bf16_t lB0[128*32], lB1[128*32];
    const bf16_t* __restrict__ A = p.A[blockIdx.z];
    const bf16_t* __restrict__ W = p.W[blockIdx.z];
    const int m0 = blockIdx.y * 128;
    const int n0 = blockIdx.x * 128;
    const int t = threadIdx.x;
    const int lane = t & 63;
    const int wave = t >> 6;
    const int wm = wave >> 1;
    const int wn = wave & 1;
    const int l16 = lane & 15;
    const int quad = lane >> 4;

    const int srow0 = wave*32 + (lane >> 2);
    const int skc   = (lane & 3) * 8;

    floatx4 acc[4][4] = {};

    for (int k0 = 0; k0 < K; k0 += 64) {
        #pragma unroll
        for (int c = 0; c < 2; ++c) {
            const int row = srow0 + c*16;
            const size_t ao = (size_t)(m0+row)*K + k0 + skc;
            const size_t wo = (size_t)(n0+row)*K + k0 + skc;
            async_cp16(&A[ao],      &lA0[row*32 + skc]);
            async_cp16(&A[ao + 32], &lA1[row*32 + skc]);
            async_cp16(&W[wo],      &lB0[row*32 + skc]);
            async_cp16(&W[wo + 32], &lB1[row*32 + skc]);
        }
        __syncthreads();
        {
            bf16x8 af[4], bfr[4];
            #pragma unroll
            for (int i = 0; i < 4; ++i) {
                af[i]  = *(const bf16x8*)(&lA0[(wm*64 + i*16 + l16)*32 + quad*8]);
                bfr[i] = *(const bf16x8*)(&lB0[(wn*64 + i*16 + l16)*32 + quad*8]);
            }
            #pragma unroll
            for (int i = 0; i < 4; ++i)
                #pragma unroll
                for (int j = 0; j < 4; ++j)
                    acc[i][j] = MFMA16(af[i], bfr[j], acc[i][j]);
        }
        {
            bf16x8 af[4], bfr[4];
            #pragma unroll
            for (int i = 0; i < 4; ++i) {
                af[i]  = *(const bf16x8*)(&lA1[(wm*64 + i*16 + l16)*32 + quad*8]);
                bfr[i] = *(const bf16x8*)(&lB1[(wn*64 + i*16 + l16)*32 + quad*8]);
            }
            #pragma unroll
            for (int i = 0; i < 4; ++i)
                #pragma unroll
                for (int j = 0; j < 4; ++j)
                    acc[i][j] = MFMA16(af[i], bfr[j], acc[i][j]);
        }
        __syncthreads();
    }

    if (MODE == 1) {
        bf16_t* __restrict__ C = (bf16_t*)p.C[blockIdx.z];
        #pragma unroll
        for (int i = 0; i < 4; ++i) {
            const int mb = m0 + wm*64 + i*16 + quad*4;
            #pragma unroll
            for (int j = 0; j < 4; ++j) {
                const int n = n0 + wn*64 + j*16 + l16;
                const int h = n >> 6, d = n & 63;
                #pragma unroll
                for (int r = 0; r < 4; ++r) {
                    const int m = mb + r;
                    const int b = m >> 11, s = m & (S_-1);
                    C[(((size_t)b*H_ + h)*S_ + s)*HD_ + d] = (bf16_t)acc[i][j][r];
                }
            }
        }
    } else {
        float* __restrict__ C = (float*)p.C[blockIdx.z];
        #pragma unroll
        for (int i = 0; i < 4; ++i) {
            const int mb = m0 + wm*64 + i*16 + quad*4;
            #pragma unroll
            for (int j = 0; j < 4; ++j) {
                const int n = n0 + wn*64 + j*16 + l16;
                #pragma unroll
                for (int r = 0; r < 4; ++r)
                    C[(size_t)(mb + r)*HDIM + n] = acc[i][j][r];
            }
        }
    }
}

// ------ RMSNorm + RoPE2D in place on q,k; v normed + transposed to [bh][d][s]
__global__ __launch_bounds__(256) void norm_rope(
    bf16_t* __restrict__ qb, bf16_t* __restrict__ kb,
    const bf16_t* __restrict__ vb, bf16_t* __restrict__ vt,
    const float* __restrict__ cs, const float* __restrict__ sn,
    const float* __restrict__ qscale, const float* __restrict__ kscale) {
    __shared__ bf16_t lv[64*65];
    const int bh = blockIdx.y;
    const int b  = bh >> 4;
    const int s0 = blockIdx.x * 64;
    const int t = threadIdx.x;
    const int wave = t >> 6;
    const int lane = t & 63;
    const float qsc = qscale[lane] * LOG2E;
    const float ksc = kscale[lane];
    const float sg = (lane & 16) ? 1.f : -1.f;

    for (int i = 0; i < 16; ++i) {
        const int s = s0 + wave*16 + i;
        const size_t addr = ((size_t)bh*S_ + s)*HD_ + lane;
        const float q = (float)qb[addr];
        const float k = (float)kb[addr];
        const float v = (float)vb[addr];
        float sq = q*q, sk = k*k, sv = v*v;
        #pragma unroll
        for (int m = 32; m; m >>= 1) {
            sq += __shfl_xor(sq, m);
            sk += __shfl_xor(sk, m);
            sv += __shfl_xor(sv, m);
        }
        float qv = q * rsqrtf(sq*(1.f/64.f) + 1e-6f) * qsc;
        float kv = k * rsqrtf(sk*(1.f/64.f) + 1e-6f) * ksc;
        const float vv = v * rsqrtf(sv*(1.f/64.f) + 1e-6f);
        const size_t ci = ((size_t)b*S_ + s)*HD_ + lane;
        const float c = cs[ci];
        const float sn_ = sn[ci];
        const float qo = __shfl_xor(qv, 16);
        const float ko = __shfl_xor(kv, 16);
        qv = qv*c + sg*qo*sn_;
        kv = kv*c + sg*ko*sn_;
        qb[addr] = (bf16_t)qv;
        kb[addr] = (bf16_t)kv;
        lv[(wave*16 + i)*65 + lane] = (bf16_t)vv;
    }
    __syncthreads();
    const int d = t >> 2;
    const int sc = (t & 3) * 16;
    bf16x8 o0, o1;
    #pragma unroll
    for (int e = 0; e < 8; ++e) {
        o0[e] = lv[(sc + e)*65 + d];
        o1[e] = lv[(sc + 8 + e)*65 + d];
    }
    bf16_t* dst = &vt[((size_t)bh*HD_ + d)*S_ + s0 + sc];
    *(bf16x8*)(dst)     = o0;
    *(bf16x8*)(dst + 8) = o1;
}

// ---------------- flash attention v5 -------------------------------------
// S^T trick: compute S^T = K Q^T (A=K, B=Q) so the exp2'd C-layout output
// (rows=keys quad*4+r, col=q=l16) IS the B-fragment (k=quad*4+j) of the
// K=16 MFMA for O^T = V^T P^T. No P LDS round-trip. L = per-lane scalar sum.
// 512 thr = 8 waves, 32 q/wave, 64-key tiles, double-buffered LDS (1 barrier
// per tile), register prefetch.
__global__ __launch_bounds__(512, 6) void flash_attn(
    const bf16_t* __restrict__ qn, const bf16_t* __restrict__ kn,
    const bf16_t* __restrict__ vt, bf16_t* __restrict__ attn_out) {
    __shared__ bf16_t lKV[2][2*64*72];   // [buf][ K(64x72) | V(64x72) ]  36.9 KB

    const int bh = blockIdx.y;
    const int b  = bh >> 4;
    const int h  = bh & 15;
    const int q0 = blockIdx.x * 256;
    const int t = threadIdx.x;
    const int wave = t >> 6;
    const int lane = t & 63;
    const int l16 = lane & 15;
    const int quad = lane >> 4;
    const floatx4 finit = {-46.f, -46.f, -46.f, -46.f};

    const bf16_t* Q  = qn + (size_t)bh * S_ * HD_;
    const bf16_t* K  = kn + (size_t)bh * S_ * HD_;
    const bf16_t* Vt = vt + (size_t)bh * HD_ * S_;

    // Q fragments (B-operand of S^T): n=q=l16, k=d=quad*8+j
    bf16x8 qf[2][2];
    #pragma unroll
    for (int rb = 0; rb < 2; ++rb) {
        const int qrow = q0 + wave*32 + rb*16 + l16;
        qf[rb][0] = *(const bf16x8*)(&Q[(size_t)qrow*HD_ + quad*8]);
        qf[rb][1] = *(const bf16x8*)(&Q[(size_t)qrow*HD_ + 32 + quad*8]);
    }

    floatx4 accO[2][4] = {};   // O^T per dt: col=q=l16, row=d_local=quad*4+reg
    float accL[2] = {0.f, 0.f};

    // staging map: thread t covers row srow=t>>3, 8 cols at skc
    const int srow = t >> 3;
    const int skc  = (t & 7) * 8;

    bf16x8 kpre = *(const bf16x8*)(&K[(size_t)srow*HD_ + skc]);
    bf16x8 vpre = *(const bf16x8*)(&Vt[(size_t)srow*S_ + skc]);
    *(bf16x8*)(&lKV[0][srow*72 + skc]) = kpre;
    *(bf16x8*)(&lKV[0][64*72 + srow*72 + skc]) = vpre;

    for (int i = 0; i < S_/64; ++i) {
        __syncthreads();                 // buf[i&1] staged for all waves
        const bf16_t* lK = lKV[i & 1];
        const bf16_t* lV = lKV[i & 1] + 64*72;
        const bool more = (i + 1 < S_/64);
        if (more) {
            const int ktn = (i + 1) * 64;
            kpre = *(const bf16x8*)(&K[(size_t)(ktn+srow)*HD_ + skc]);
            vpre = *(const bf16x8*)(&Vt[(size_t)srow*S_ + ktn + skc]);
        }

        // S^T = K Q^T - 46 ; P^T = exp2  (stays in registers as B-frags)
        shortx4 pf[2][4];
        #pragma unroll
        for (int ct = 0; ct < 4; ++ct) {
            const bf16x8 kf0 = *(const bf16x8*)(&lK[(ct*16+l16)*72 + quad*8]);
            const bf16x8 kf1 = *(const bf16x8*)(&lK[(ct*16+l16)*72 + 32 + quad*8]);
            #pragma unroll
            for (int rb = 0; rb < 2; ++rb) {
                floatx4 s = MFMA16(kf0, qf[rb][0], finit);
                s = MFMA16(kf1, qf[rb][1], s);
                bf16x4 pb;
                float e0 = __builtin_amdgcn_exp2f(s[0]);
                float e1 = __builtin_amdgcn_exp2f(s[1]);
                float e2 = __builtin_amdgcn_exp2f(s[2]);
                float e3 = __builtin_amdgcn_exp2f(s[3]);
                accL[rb] += (e0 + e1) + (e2 + e3);
                pb[0] = (bf16_t)e0; pb[1] = (bf16_t)e1;
                pb[2] = (bf16_t)e2; pb[3] = (bf16_t)e3;
                pf[rb][ct] = __builtin_bit_cast(shortx4, pb);
            }
        }

        // O^T += V^T P^T  (A = V^T b64 frags from lV; B = pf in registers)
        #pragma unroll
        for (int dt = 0; dt < 4; ++dt) {
            #pragma unroll
            for (int ct = 0; ct < 4; ++ct) {
                const bf16x4 vh = *(const bf16x4*)(&lV[(dt*16+l16)*72 + ct*16 + quad*4]);
                const shortx4 vf = __builtin_bit_cast(shortx4, vh);
                accO[0][dt] = MFMA1K(vf, pf[0][ct], accO[0][dt]);
                accO[1][dt] = MFMA1K(vf, pf[1][ct], accO[1][dt]);
            }
        }

        if (more) {
            bf16_t* nK = lKV[(i+1) & 1];
            *(bf16x8*)(&nK[srow*72 + skc]) = kpre;
            *(bf16x8*)(&nK[64*72 + srow*72 + skc]) = vpre;
        }
    }

    // epilogue: reduce L across quads, transpose O^T via (now free) lKV[0]
    bf16_t* W = &lKV[0][wave * 16 * 72];   // per-wave 16 q-rows x 72
    #pragma unroll
    for (int rb = 0; rb < 2; ++rb) {
        float lr = accL[rb];
        lr += __shfl_xor(lr, 16);
        lr += __shfl_xor(lr, 32);
        const float inv = 1.f / lr;        // L[q=l16]
        #pragma unroll
        for (int dt = 0; dt < 4; ++dt)
            #pragma unroll
            for (int r = 0; r < 4; ++r)
                W[l16*72 + dt*16 + quad*4 + r] = (bf16_t)(accO[rb][dt][r] * inv);
        // coalesced write: 8 lanes per q-row, 16 B each
        #pragma unroll
        for (int half = 0; half < 2; ++half) {
            const int qr = half*8 + (lane >> 3);
            const bf16x8 o = *(const bf16x8*)(&W[qr*72 + (lane & 7)*8]);
            const int srw = q0 + wave*32 + rb*16 + qr;
            *(bf16x8*)(&attn_out[((size_t)b*S_ + srw)*HDIM + h*HD_ + (lane & 7)*8]) = o;
        }
    }
}

extern "C" void kernel_launch(void* const* d_in, const int* in_sizes, int n_in,
                              void* d_out, int out_size, void* d_ws, size_t ws_size,
                              hipStream_t stream) {
    (void)in_sizes; (void)n_in; (void)out_size; (void)ws_size;
    const float* X  = (const float*)d_in[0];
    const float* cs = (const float*)d_in[1];
    const float* sn = (const float*)d_in[2];
    const float* wq = (const float*)d_in[4];
    const float* wk = (const float*)d_in[5];
    const float* wv = (const float*)d_in[6];
    const float* wo = (const float*)d_in[7];
    const float* qs = (const float*)d_in[8];
    const float* ks = (const float*)d_in[9];
    float* out = (float*)d_out;

    const size_t PROJ = (size_t)NTOK * HDIM;
    const size_t WSZ  = (size_t)HDIM * D_;
    bf16_t* ws   = (bf16_t*)d_ws;
    bf16_t* Xb   = ws;                 // dead after gemm1 -> reused as vt
    bf16_t* wqb  = ws + PROJ;
    bf16_t* wkb  = wqb + WSZ;
    bf16_t* wvb  = wkb + WSZ;
    bf16_t* wob  = wvb + WSZ;
    bf16_t* qb   = wob + WSZ;
    bf16_t* kb   = qb + PROJ;
    bf16_t* vb   = kb + PROJ;          // dead after norm_rope -> reused as attn
    bf16_t* vt   = Xb;
    bf16_t* attn = vb;                 // total ws: 72 MB

    Cvt5 cp;
    cp.s[0] = X;  cp.d[0] = Xb;  cp.n4[0] = (int)(PROJ/4);
    cp.s[1] = wq; cp.d[1] = wqb; cp.n4[1] = (int)(WSZ/4);
    cp.s[2] = wk; cp.d[2] = wkb; cp.n4[2] = (int)(WSZ/4);
    cp.s[3] = wv; cp.d[3] = wvb; cp.n4[3] = (int)(WSZ/4);
    cp.s[4] = wo; cp.d[4] = wob; cp.n4[4] = (int)(WSZ/4);
    cvt5<<<dim3(1024, 5), 256, 0, stream>>>(cp);

    GemmPtrs g1;
    g1.A[0] = Xb;  g1.A[1] = Xb;  g1.A[2] = Xb;
    g1.W[0] = wqb; g1.W[1] = wkb; g1.W[2] = wvb;
    g1.C[0] = qb;  g1.C[1] = kb;  g1.C[2] = vb;
    gemm_nt<1><<<dim3(HDIM/128, NTOK/128, 3), 256, 0, stream>>>(g1, D_);

    norm_rope<<<dim3(S_/64, B_*H_), 256, 0, stream>>>(qb, kb, vb, vt, cs, sn, qs, ks);

    flash_attn<<<dim3(S_/256, B_*H_), 512, 0, stream>>>(qb, kb, vt, attn);

    GemmPtrs g2;
    g2.A[0] = attn; g2.W[0] = wob; g2.C[0] = out;
    g2.A[1] = attn; g2.W[1] = wob; g2.C[1] = out;
    g2.A[2] = attn; g2.W[2] = wob; g2.C[2] = out;
    gemm_nt<2><<<dim3(HDIM/128, NTOK/128, 1), 256, 0, stream>>>(g2, HDIM);
}

// Round 8
// 343.978 us; speedup vs baseline: 1.8238x; 1.8238x over previous
//
#include <hip/hip_runtime.h>
#include <hip/hip_bf16.h>
#include <stdint.h>
#include <stddef.h>

#define B_ 4
#define S_ 2048
#define D_ 1024
#define H_ 16
#define HD_ 64
#define NTOK (B_*S_)      // 8192
#define HDIM (H_*HD_)     // 1024
#define LOG2E 1.44269504088896f

typedef __bf16 bf16_t;
typedef __bf16 bf16x4 __attribute__((ext_vector_type(4)));
typedef __bf16 bf16x8 __attribute__((ext_vector_type(8)));
typedef short shortx4 __attribute__((ext_vector_type(4)));
typedef float floatx4 __attribute__((ext_vector_type(4)));

#define MFMA16(a,b,c)  __builtin_amdgcn_mfma_f32_16x16x32_bf16((a),(b),(c),0,0,0)
#define MFMA1K(a,b,c)  __builtin_amdgcn_mfma_f32_16x16x16bf16_1k((a),(b),(c),0,0,0)

// async global->LDS, 16 B per lane; LDS dst must be wave-uniform-base + lane*16
__device__ __forceinline__ void async_cp16(const bf16_t* g, bf16_t* l) {
    typedef __attribute__((address_space(1))) const unsigned int gu32;
    typedef __attribute__((address_space(3))) unsigned int lu32;
    __builtin_amdgcn_global_load_lds((gu32*)g, (lu32*)l, 16, 0, 0);
}

// ---------------- fp32 -> bf16 bulk convert (5 segments) ----------------
struct Cvt5 { const float* s[5]; bf16_t* d[5]; int n4[5]; };

__global__ __launch_bounds__(256) void cvt5(Cvt5 p) {
    const int z = blockIdx.y;
    const float4* __restrict__ src = (const float4*)p.s[z];
    bf16x4* __restrict__ dst = (bf16x4*)p.d[z];
    const int n4 = p.n4[z];
    for (int i = blockIdx.x * 256 + threadIdx.x; i < n4; i += gridDim.x * 256) {
        const float4 v = src[i];
        dst[i] = (bf16x4){(bf16_t)v.x, (bf16_t)v.y, (bf16_t)v.z, (bf16_t)v.w};
    }
}

// ---------------- NT GEMM, BK=64 (dual stride-32 buffers) -----------------
struct GemmPtrs { const bf16_t* A[3]; const bf16_t* W[3]; void* C[3]; };

template<int MODE>
__global__ __launch_bounds__(256, 3) void gemm_nt(GemmPtrs p, int K) {
    __shared__ bf16_t lA0[128*32], lA1[128*32];
    __shared__ bf16_t lB0[128*32], lB1[128*32];
    const bf16_t* __restrict__ A = p.A[blockIdx.z];
    const bf16_t* __restrict__ W = p.W[blockIdx.z];
    const int m0 = blockIdx.y * 128;
    const int n0 = blockIdx.x * 128;
    const int t = threadIdx.x;
    const int lane = t & 63;
    const int wave = t >> 6;
    const int wm = wave >> 1;
    const int wn = wave & 1;
    const int l16 = lane & 15;
    const int quad = lane >> 4;

    const int srow0 = wave*32 + (lane >> 2);
    const int skc   = (lane & 3) * 8;

    floatx4 acc[4][4] = {};

    for (int k0 = 0; k0 < K; k0 += 64) {
        #pragma unroll
        for (int c = 0; c < 2; ++c) {
            const int row = srow0 + c*16;
            const size_t ao = (size_t)(m0+row)*K + k0 + skc;
            const size_t wo = (size_t)(n0+row)*K + k0 + skc;
            async_cp16(&A[ao],      &lA0[row*32 + skc]);
            async_cp16(&A[ao + 32], &lA1[row*32 + skc]);
            async_cp16(&W[wo],      &lB0[row*32 + skc]);
            async_cp16(&W[wo + 32], &lB1[row*32 + skc]);
        }
        __syncthreads();
        {
            bf16x8 af[4], bfr[4];
            #pragma unroll
            for (int i = 0; i < 4; ++i) {
                af[i]  = *(const bf16x8*)(&lA0[(wm*64 + i*16 + l16)*32 + quad*8]);
                bfr[i] = *(const bf16x8*)(&lB0[(wn*64 + i*16 + l16)*32 + quad*8]);
            }
            #pragma unroll
            for (int i = 0; i < 4; ++i)
                #pragma unroll
                for (int j = 0; j < 4; ++j)
                    acc[i][j] = MFMA16(af[i], bfr[j], acc[i][j]);
        }
        {
            bf16x8 af[4], bfr[4];
            #pragma unroll
            for (int i = 0; i < 4; ++i) {
                af[i]  = *(const bf16x8*)(&lA1[(wm*64 + i*16 + l16)*32 + quad*8]);
                bfr[i] = *(const bf16x8*)(&lB1[(wn*64 + i*16 + l16)*32 + quad*8]);
            }
            #pragma unroll
            for (int i = 0; i < 4; ++i)
                #pragma unroll
                for (int j = 0; j < 4; ++j)
                    acc[i][j] = MFMA16(af[i], bfr[j], acc[i][j]);
        }
        __syncthreads();
    }

    if (MODE == 1) {
        bf16_t* __restrict__ C = (bf16_t*)p.C[blockIdx.z];
        #pragma unroll
        for (int i = 0; i < 4; ++i) {
            const int mb = m0 + wm*64 + i*16 + quad*4;
            #pragma unroll
            for (int j = 0; j < 4; ++j) {
                const int n = n0 + wn*64 + j*16 + l16;
                const int h = n >> 6, d = n & 63;
                #pragma unroll
                for (int r = 0; r < 4; ++r) {
                    const int m = mb + r;
                    const int b = m >> 11, s = m & (S_-1);
                    C[(((size_t)b*H_ + h)*S_ + s)*HD_ + d] = (bf16_t)acc[i][j][r];
                }
            }
        }
    } else {
        float* __restrict__ C = (float*)p.C[blockIdx.z];
        #pragma unroll
        for (int i = 0; i < 4; ++i) {
            const int mb = m0 + wm*64 + i*16 + quad*4;
            #pragma unroll
            for (int j = 0; j < 4; ++j) {
                const int n = n0 + wn*64 + j*16 + l16;
                #pragma unroll
                for (int r = 0; r < 4; ++r)
                    C[(size_t)(mb + r)*HDIM + n] = acc[i][j][r];
            }
        }
    }
}

// ------ RMSNorm + RoPE2D in place on q,k; v normed + transposed to [bh][d][s]
__global__ __launch_bounds__(256) void norm_rope(
    bf16_t* __restrict__ qb, bf16_t* __restrict__ kb,
    const bf16_t* __restrict__ vb, bf16_t* __restrict__ vt,
    const float* __restrict__ cs, const float* __restrict__ sn,
    const float* __restrict__ qscale, const float* __restrict__ kscale) {
    __shared__ bf16_t lv[64*65];
    const int bh = blockIdx.y;
    const int b  = bh >> 4;
    const int s0 = blockIdx.x * 64;
    const int t = threadIdx.x;
    const int wave = t >> 6;
    const int lane = t & 63;
    const float qsc = qscale[lane] * LOG2E;
    const float ksc = kscale[lane];
    const float sg = (lane & 16) ? 1.f : -1.f;

    for (int i = 0; i < 16; ++i) {
        const int s = s0 + wave*16 + i;
        const size_t addr = ((size_t)bh*S_ + s)*HD_ + lane;
        const float q = (float)qb[addr];
        const float k = (float)kb[addr];
        const float v = (float)vb[addr];
        float sq = q*q, sk = k*k, sv = v*v;
        #pragma unroll
        for (int m = 32; m; m >>= 1) {
            sq += __shfl_xor(sq, m);
            sk += __shfl_xor(sk, m);
            sv += __shfl_xor(sv, m);
        }
        float qv = q * rsqrtf(sq*(1.f/64.f) + 1e-6f) * qsc;
        float kv = k * rsqrtf(sk*(1.f/64.f) + 1e-6f) * ksc;
        const float vv = v * rsqrtf(sv*(1.f/64.f) + 1e-6f);
        const size_t ci = ((size_t)b*S_ + s)*HD_ + lane;
        const float c = cs[ci];
        const float sn_ = sn[ci];
        const float qo = __shfl_xor(qv, 16);
        const float ko = __shfl_xor(kv, 16);
        qv = qv*c + sg*qo*sn_;
        kv = kv*c + sg*ko*sn_;
        qb[addr] = (bf16_t)qv;
        kb[addr] = (bf16_t)kv;
        lv[(wave*16 + i)*65 + lane] = (bf16_t)vv;
    }
    __syncthreads();
    const int d = t >> 2;
    const int sc = (t & 3) * 16;
    bf16x8 o0, o1;
    #pragma unroll
    for (int e = 0; e < 8; ++e) {
        o0[e] = lv[(sc + e)*65 + d];
        o1[e] = lv[(sc + 8 + e)*65 + d];
    }
    bf16_t* dst = &vt[((size_t)bh*HD_ + d)*S_ + s0 + sc];
    *(bf16x8*)(dst)     = o0;
    *(bf16x8*)(dst + 8) = o1;
}

// ---------------- flash attention v5.1 ------------------------------------
// S^T trick: S^T = K Q^T so exp2'd C-layout output IS the B-fragment of the
// K=16 MFMA for O^T = V^T P^T. No P LDS round-trip. L = per-lane scalar sum.
// launch_bounds (512,4): (512,6) in v5 capped VGPRs at ~85 -> accumulator
// spill to scratch (FETCH 139->770 MB, WRITE 16MB->1.08GB). 128-cap fits
// the ~100-reg live set with zero spill.
__global__ __launch_bounds__(512, 4) void flash_attn(
    const bf16_t* __restrict__ qn, const bf16_t* __restrict__ kn,
    const bf16_t* __restrict__ vt, bf16_t* __restrict__ attn_out) {
    __shared__ bf16_t lKV[2][2*64*72];   // [buf][ K(64x72) | V(64x72) ]  36.9 KB

    const int bh = blockIdx.y;
    const int b  = bh >> 4;
    const int h  = bh & 15;
    const int q0 = blockIdx.x * 256;
    const int t = threadIdx.x;
    const int wave = t >> 6;
    const int lane = t & 63;
    const int l16 = lane & 15;
    const int quad = lane >> 4;
    const floatx4 finit = {-46.f, -46.f, -46.f, -46.f};

    const bf16_t* Q  = qn + (size_t)bh * S_ * HD_;
    const bf16_t* K  = kn + (size_t)bh * S_ * HD_;
    const bf16_t* Vt = vt + (size_t)bh * HD_ * S_;

    // Q fragments (B-operand of S^T): n=q=l16, k=d=quad*8+j
    bf16x8 qf[2][2];
    #pragma unroll
    for (int rb = 0; rb < 2; ++rb) {
        const int qrow = q0 + wave*32 + rb*16 + l16;
        qf[rb][0] = *(const bf16x8*)(&Q[(size_t)qrow*HD_ + quad*8]);
        qf[rb][1] = *(const bf16x8*)(&Q[(size_t)qrow*HD_ + 32 + quad*8]);
    }

    floatx4 accO[2][4] = {};   // O^T per dt: col=q=l16, row=d_local=quad*4+reg
    float accL[2] = {0.f, 0.f};

    // staging map: thread t covers row srow=t>>3, 8 cols at skc
    const int srow = t >> 3;
    const int skc  = (t & 7) * 8;

    bf16x8 kpre = *(const bf16x8*)(&K[(size_t)srow*HD_ + skc]);
    bf16x8 vpre = *(const bf16x8*)(&Vt[(size_t)srow*S_ + skc]);
    *(bf16x8*)(&lKV[0][srow*72 + skc]) = kpre;
    *(bf16x8*)(&lKV[0][64*72 + srow*72 + skc]) = vpre;

    for (int i = 0; i < S_/64; ++i) {
        __syncthreads();                 // buf[i&1] staged for all waves
        const bf16_t* lK = lKV[i & 1];
        const bf16_t* lV = lKV[i & 1] + 64*72;
        const bool more = (i + 1 < S_/64);
        if (more) {
            const int ktn = (i + 1) * 64;
            kpre = *(const bf16x8*)(&K[(size_t)(ktn+srow)*HD_ + skc]);
            vpre = *(const bf16x8*)(&Vt[(size_t)srow*S_ + ktn + skc]);
        }

        // S^T = K Q^T - 46 ; P^T = exp2  (stays in registers as B-frags)
        shortx4 pf[2][4];
        #pragma unroll
        for (int ct = 0; ct < 4; ++ct) {
            const bf16x8 kf0 = *(const bf16x8*)(&lK[(ct*16+l16)*72 + quad*8]);
            const bf16x8 kf1 = *(const bf16x8*)(&lK[(ct*16+l16)*72 + 32 + quad*8]);
            #pragma unroll
            for (int rb = 0; rb < 2; ++rb) {
                floatx4 s = MFMA16(kf0, qf[rb][0], finit);
                s = MFMA16(kf1, qf[rb][1], s);
                bf16x4 pb;
                float e0 = __builtin_amdgcn_exp2f(s[0]);
                float e1 = __builtin_amdgcn_exp2f(s[1]);
                float e2 = __builtin_amdgcn_exp2f(s[2]);
                float e3 = __builtin_amdgcn_exp2f(s[3]);
                accL[rb] += (e0 + e1) + (e2 + e3);
                pb[0] = (bf16_t)e0; pb[1] = (bf16_t)e1;
                pb[2] = (bf16_t)e2; pb[3] = (bf16_t)e3;
                pf[rb][ct] = __builtin_bit_cast(shortx4, pb);
            }
        }

        // O^T += V^T P^T  (A = V^T b64 frags from lV; B = pf in registers)
        #pragma unroll
        for (int dt = 0; dt < 4; ++dt) {
            #pragma unroll
            for (int ct = 0; ct < 4; ++ct) {
                const bf16x4 vh = *(const bf16x4*)(&lV[(dt*16+l16)*72 + ct*16 + quad*4]);
                const shortx4 vf = __builtin_bit_cast(shortx4, vh);
                accO[0][dt] = MFMA1K(vf, pf[0][ct], accO[0][dt]);
                accO[1][dt] = MFMA1K(vf, pf[1][ct], accO[1][dt]);
            }
        }

        if (more) {
            bf16_t* nK = lKV[(i+1) & 1];
            *(bf16x8*)(&nK[srow*72 + skc]) = kpre;
            *(bf16x8*)(&nK[64*72 + srow*72 + skc]) = vpre;
        }
    }

    // epilogue: reduce L across quads, transpose O^T via (now free) lKV[0]
    bf16_t* W = &lKV[0][wave * 16 * 72];   // per-wave 16 q-rows x 72
    #pragma unroll
    for (int rb = 0; rb < 2; ++rb) {
        float lr = accL[rb];
        lr += __shfl_xor(lr, 16);
        lr += __shfl_xor(lr, 32);
        const float inv = 1.f / lr;        // L[q=l16]
        #pragma unroll
        for (int dt = 0; dt < 4; ++dt)
            #pragma unroll
            for (int r = 0; r < 4; ++r)
                W[l16*72 + dt*16 + quad*4 + r] = (bf16_t)(accO[rb][dt][r] * inv);
        // coalesced write: 8 lanes per q-row, 16 B each
        #pragma unroll
        for (int half = 0; half < 2; ++half) {
            const int qr = half*8 + (lane >> 3);
            const bf16x8 o = *(const bf16x8*)(&W[qr*72 + (lane & 7)*8]);
            const int srw = q0 + wave*32 + rb*16 + qr;
            *(bf16x8*)(&attn_out[((size_t)b*S_ + srw)*HDIM + h*HD_ + (lane & 7)*8]) = o;
        }
    }
}

extern "C" void kernel_launch(void* const* d_in, const int* in_sizes, int n_in,
                              void* d_out, int out_size, void* d_ws, size_t ws_size,
                              hipStream_t stream) {
    (void)in_sizes; (void)n_in; (void)out_size; (void)ws_size;
    const float* X  = (const float*)d_in[0];
    const float* cs = (const float*)d_in[1];
    const float* sn = (const float*)d_in[2];
    const float* wq = (const float*)d_in[4];
    const float* wk = (const float*)d_in[5];
    const float* wv = (const float*)d_in[6];
    const float* wo = (const float*)d_in[7];
    const float* qs = (const float*)d_in[8];
    const float* ks = (const float*)d_in[9];
    float* out = (float*)d_out;

    const size_t PROJ = (size_t)NTOK * HDIM;
    const size_t WSZ  = (size_t)HDIM * D_;
    bf16_t* ws   = (bf16_t*)d_ws;
    bf16_t* Xb   = ws;                 // dead after gemm1 -> reused as vt
    bf16_t* wqb  = ws + PROJ;
    bf16_t* wkb  = wqb + WSZ;
    bf16_t* wvb  = wkb + WSZ;
    bf16_t* wob  = wvb + WSZ;
    bf16_t* qb   = wob + WSZ;
    bf16_t* kb   = qb + PROJ;
    bf16_t* vb   = kb + PROJ;          // dead after norm_rope -> reused as attn
    bf16_t* vt   = Xb;
    bf16_t* attn = vb;                 // total ws: 72 MB

    Cvt5 cp;
    cp.s[0] = X;  cp.d[0] = Xb;  cp.n4[0] = (int)(PROJ/4);
    cp.s[1] = wq; cp.d[1] = wqb; cp.n4[1] = (int)(WSZ/4);
    cp.s[2] = wk; cp.d[2] = wkb; cp.n4[2] = (int)(WSZ/4);
    cp.s[3] = wv; cp.d[3] = wvb; cp.n4[3] = (int)(WSZ/4);
    cp.s[4] = wo; cp.d[4] = wob; cp.n4[4] = (int)(WSZ/4);
    cvt5<<<dim3(1024, 5), 256, 0, stream>>>(cp);

    GemmPtrs g1;
    g1.A[0] = Xb;  g1.A[1] = Xb;  g1.A[2] = Xb;
    g1.W[0] = wqb; g1.W[1] = wkb; g1.W[2] = wvb;
    g1.C[0] = qb;  g1.C[1] = kb;  g1.C[2] = vb;
    gemm_nt<1><<<dim3(HDIM/128, NTOK/128, 3), 256, 0, stream>>>(g1, D_);

    norm_rope<<<dim3(S_/64, B_*H_), 256, 0, stream>>>(qb, kb, vb, vt, cs, sn, qs, ks);

    flash_attn<<<dim3(S_/256, B_*H_), 512, 0, stream>>>(qb, kb, vt, attn);

    GemmPtrs g2;
    g2.A[0] = attn; g2.W[0] = wob; g2.C[0] = out;
    g2.A[1] = attn; g2.W[1] = wob; g2.C[1] = out;
    g2.A[2] = attn; g2.W[2] = wob; g2.C[2] = out;
    gemm_nt<2><<<dim3(HDIM/128, NTOK/128, 1), 256, 0, stream>>>(g2, HDIM);
}